// Round 1
// baseline (126.790 us; speedup 1.0000x reference)
//
#include <hip/hip_runtime.h>

// Involution2d: B=8, C=256, G=4 (Cpg=64), H=W=Ho=Wo=64, K=7, PAD=3, STRIDE=1.
// out[b, g*64+c, y, x] = sum_{kh,kw} in[b, g*64+c, y+kh-3, x+kw-3] * w[b,g,kh,kw,y,x] + bias[g*64+c]
//
// Strategy: weights (vary per pixel, reused across 64 channels) live in VGPRs
// (49 x float4 per thread); input staged per-channel in LDS with a register
// sliding window in x (TX=4). Thread = (x-quad, y-row); block covers 8 rows x
// full width for one (b,g), 16 channels. Register prefetch double-buffers the
// per-channel staging.

#define BLK_X 16   // x-quads -> 64 x positions
#define BLK_Y 8    // y rows per tile
#define NTHR (BLK_X * BLK_Y)      // 128
#define STG_ROWS 14               // 8 + 6 halo
#define STG_COLS 70               // 64 + 6 halo
#define STG_N (STG_ROWS * STG_COLS)   // 980
#define LDS_STRIDE 71             // odd stride: breaks 4-way bank parity
#define NSTG 8                    // ceil(980/128)
#define CH_PER_BLK 16

__global__ __launch_bounds__(NTHR, 2)
void involution_kernel(const float* __restrict__ in,
                       const float* __restrict__ w,
                       const float* __restrict__ bias,
                       float* __restrict__ out) {
    __shared__ float lds[STG_ROWS * LDS_STRIDE];

    const int tx = threadIdx.x;          // 0..15
    const int ty = threadIdx.y;          // 0..7
    const int tid = ty * BLK_X + tx;     // 0..127
    const int x0 = tx * 4;
    const int Y0 = blockIdx.x * BLK_Y;
    const int y  = Y0 + ty;
    const int c0 = blockIdx.y * CH_PER_BLK;   // channel-in-group base
    const int bz = blockIdx.z;                // b*4 + g
    const int g  = bz & 3;

    // ---- weight prologue: 49 aligned float4 loads, coalesced across tx ----
    float4 w4[49];
    const float* wb = w + (size_t)bz * 49 * 4096 + y * 64 + x0;
    #pragma unroll
    for (int k = 0; k < 49; ++k) {
        w4[k] = *(const float4*)(wb + (size_t)k * 4096);
    }

    const float* inb  = in  + (size_t)bz * 64 * 4096;  // (b*256 + g*64) plane base
    float*       outb = out + (size_t)bz * 64 * 4096;

    // ---- staging helpers ----
    // logical index i in [0, 980): row r = i/70, col = i%70
    // global: gy = Y0 + r - 3, gx = col - 3, zero-fill out of bounds
    float stg[NSTG];

    auto load_c = [&](int c, float* r) {
        const float* p = inb + (size_t)c * 4096;
        #pragma unroll
        for (int j = 0; j < NSTG; ++j) {
            int i = tid + j * NTHR;
            float v = 0.f;
            if (i < STG_N) {
                int rr = i / STG_COLS;
                int cc = i - rr * STG_COLS;
                int gy = Y0 + rr - 3;
                int gx = cc - 3;
                if (gy >= 0 && gy < 64 && gx >= 0 && gx < 64)
                    v = p[gy * 64 + gx];
            }
            r[j] = v;
        }
    };
    auto write_stage = [&](const float* r) {
        #pragma unroll
        for (int j = 0; j < NSTG; ++j) {
            int i = tid + j * NTHR;
            if (i < STG_N) {
                int rr = i / STG_COLS;
                int cc = i - rr * STG_COLS;
                lds[rr * LDS_STRIDE + cc] = r[j];
            }
        }
    };

    load_c(c0, stg);
    write_stage(stg);
    __syncthreads();

    for (int cc = 0; cc < CH_PER_BLK; ++cc) {
        const int c = c0 + cc;

        // register-prefetch next channel (overlaps with compute below)
        float nstg[NSTG];
        if (cc + 1 < CH_PER_BLK) load_c(c + 1, nstg);

        float acc0 = 0.f, acc1 = 0.f, acc2 = 0.f, acc3 = 0.f;
        #pragma unroll
        for (int kh = 0; kh < 7; ++kh) {
            const float* lrow = &lds[(ty + kh) * LDS_STRIDE + x0];
            float vals[10];
            #pragma unroll
            for (int j = 0; j < 10; ++j) vals[j] = lrow[j];
            #pragma unroll
            for (int kw = 0; kw < 7; ++kw) {
                const float4 wv = w4[kh * 7 + kw];
                acc0 += vals[kw + 0] * wv.x;
                acc1 += vals[kw + 1] * wv.y;
                acc2 += vals[kw + 2] * wv.z;
                acc3 += vals[kw + 3] * wv.w;
            }
        }

        const float bv = bias[g * 64 + c];
        float4 o;
        o.x = acc0 + bv; o.y = acc1 + bv; o.z = acc2 + bv; o.w = acc3 + bv;
        *(float4*)(outb + (size_t)c * 4096 + y * 64 + x0) = o;

        if (cc + 1 < CH_PER_BLK) {
            __syncthreads();           // everyone done reading lds
            write_stage(nstg);
            __syncthreads();           // staging visible
        }
    }
}

extern "C" void kernel_launch(void* const* d_in, const int* in_sizes, int n_in,
                              void* d_out, int out_size, void* d_ws, size_t ws_size,
                              hipStream_t stream) {
    const float* in   = (const float*)d_in[0];  // (8,256,64,64)
    const float* wgt  = (const float*)d_in[1];  // (8,4,7,7,64,64)
    const float* bias = (const float*)d_in[2];  // (256,)
    float* out = (float*)d_out;                 // (8,256,64,64)

    dim3 block(BLK_X, BLK_Y, 1);                // 128 threads
    dim3 grid(64 / BLK_Y, 64 / CH_PER_BLK, 32); // (8, 4, 32) = 1024 blocks
    involution_kernel<<<grid, block, 0, stream>>>(in, wgt, bias, out);
}